// Round 1
// baseline (16.896 us; speedup 1.0000x reference)
//
#include <hip/hip_runtime.h>
#include <hip/hip_bf16.h>

// Problem constants (fixed by the reference module)
constexpr int B    = 8;
constexpr int LS   = 256;          // L_SRC == L_TGT
constexpr int L    = 512;          // L_SRC + L_TGT
constexpr int H    = 768;
constexpr int S    = 128;          // N_SRC_WORDS
constexpr int T    = 128;          // N_TGT_WORDS
constexpr int NW   = 256;          // S + T (pooled words used)
constexpr int NSEG = 513;          // worst-case run count (<= L) + overflow slot

// ---------------------------------------------------------------------------
// Kernel 1: per-batch run segmentation + per-segment counts; zero the sums.
// 8 blocks x 64 threads (1 wave). Each lane owns 8 contiguous tokens; local
// prefix over its chunk, then wave-level exclusive scan via __shfl_up.
// ---------------------------------------------------------------------------
__global__ __launch_bounds__(64) void seg_count_kernel(
    const int* __restrict__ mask, const int* __restrict__ sw,
    const int* __restrict__ tw, int* __restrict__ seg,
    float* __restrict__ sums, float* __restrict__ cnts)
{
    const int b    = blockIdx.x;
    const int lane = threadIdx.x;

    __shared__ float lcnt[NSEG];
    for (int i = lane; i < NSEG; i += 64) lcnt[i] = 0.f;
    __syncthreads();

    const int base = lane * 8;
    int  wid[8]; bool val[8];
    #pragma unroll
    for (int j = 0; j < 8; ++j) {
        const int l = base + j;
        const int w = (l < LS) ? sw[b * LS + l] : tw[b * LS + (l - LS)];
        wid[j] = w;
        val[j] = (mask[b * L + l] > 0) && (w >= 0);
    }

    int pw = -2; bool pv = false;
    if (base > 0) {
        const int l = base - 1;
        pw = (l < LS) ? sw[b * LS + l] : tw[b * LS + (l - LS)];
        pv = (mask[b * L + l] > 0) && (pw >= 0);
    }

    int loc[8]; int c = 0;
    #pragma unroll
    for (int j = 0; j < 8; ++j) {
        const int nr = (val[j] && (wid[j] != pw || !pv)) ? 1 : 0;
        c += nr;
        loc[j] = c;
        pw = wid[j]; pv = val[j];
    }

    // wave inclusive scan of per-lane totals -> exclusive offset
    int inc = c;
    #pragma unroll
    for (int off = 1; off < 64; off <<= 1) {
        const int v = __shfl_up(inc, off);
        if (lane >= off) inc += v;
    }
    const int excl = inc - c;

    #pragma unroll
    for (int j = 0; j < 8; ++j) {
        const int rid = excl + loc[j] - 1;
        int sg = val[j] ? rid : NW;
        if (sg > NSEG - 1) sg = NSEG - 1;   // safety clamp
        seg[b * L + base + j] = sg;
        atomicAdd(&lcnt[sg], 1.0f);
    }
    __syncthreads();

    for (int i = lane; i < NSEG; i += 64) {
        cnts[b * NSEG + i] = lcnt[i];
        sums[b * NSEG + i] = 0.f;           // zero accumulators (ws is poisoned)
    }
}

// ---------------------------------------------------------------------------
// Kernel 2: one wave per token; dot(tok_h[b,l,:], w_half(seg)) -> atomicAdd
// into sums[b, seg]. Skips invalid / out-of-range segments (wave-uniform).
// ---------------------------------------------------------------------------
__global__ __launch_bounds__(256) void dot_kernel(
    const float* __restrict__ tok, const float* __restrict__ Wp,
    const int* __restrict__ seg, float* __restrict__ sums)
{
    const int lane  = threadIdx.x & 63;
    const int wv    = threadIdx.x >> 6;
    const int token = blockIdx.x * 4 + wv;      // 0 .. B*L-1
    const int b     = token >> 9;               // /L

    const int sg = seg[token];
    if (sg >= NW) return;                       // invalid or beyond pooled range

    const float* wvec = Wp + ((sg < S) ? 0 : H);
    const float4* t4  = reinterpret_cast<const float4*>(tok + (size_t)token * H);
    const float4* w4  = reinterpret_cast<const float4*>(wvec);

    float acc = 0.f;
    #pragma unroll
    for (int k = 0; k < 3; ++k) {               // 3 * 64 * 4 = 768
        const float4 a = t4[lane + 64 * k];
        const float4 w = w4[lane + 64 * k];
        acc += a.x * w.x + a.y * w.y + a.z * w.z + a.w * w.w;
    }
    #pragma unroll
    for (int off = 32; off; off >>= 1) acc += __shfl_xor(acc, off);

    if (lane == 0) atomicAdd(&sums[b * NSEG + sg], acc);
}

// ---------------------------------------------------------------------------
// Kernel 3: finalize means, broadcast-sum into logits. 8 blocks x 256 thr.
// ---------------------------------------------------------------------------
__global__ __launch_bounds__(256) void logits_kernel(
    const float* __restrict__ sums, const float* __restrict__ cnts,
    const float* __restrict__ bias, float* __restrict__ out)
{
    const int b   = blockIdx.x;
    const int tid = threadIdx.x;

    __shared__ float ssrc[S], stgt[T];
    if (tid < S) {
        ssrc[tid] = sums[b * NSEG + tid] / fmaxf(cnts[b * NSEG + tid], 1.f);
    } else {
        const int j = tid - S;                  // 0..T-1 (block=256=S+T)
        stgt[j] = sums[b * NSEG + S + j] / fmaxf(cnts[b * NSEG + S + j], 1.f);
    }
    __syncthreads();

    const float b0 = bias[0];
    const int i  = tid >> 1;                    // row 0..127
    const int jb = (tid & 1) * 64;              // col half
    const float si = ssrc[i] + b0;

    float4* o = reinterpret_cast<float4*>(out + (size_t)b * S * T + i * T + jb);
    #pragma unroll
    for (int j = 0; j < 64; j += 4) {
        float4 v;
        v.x = si + stgt[jb + j + 0];
        v.y = si + stgt[jb + j + 1];
        v.z = si + stgt[jb + j + 2];
        v.w = si + stgt[jb + j + 3];
        o[j >> 2] = v;
    }
}

extern "C" void kernel_launch(void* const* d_in, const int* in_sizes, int n_in,
                              void* d_out, int out_size, void* d_ws, size_t ws_size,
                              hipStream_t stream) {
    const float* tok  = (const float*)d_in[0];   // (B, L, H) f32
    const int*   mask = (const int*)  d_in[1];   // (B, L)
    const int*   sw   = (const int*)  d_in[2];   // (B, LS)
    const int*   tw   = (const int*)  d_in[3];   // (B, LS)
    const float* W    = (const float*)d_in[4];   // (2H, 1)
    const float* bias = (const float*)d_in[5];   // (1,)
    float*       out  = (float*)d_out;           // (B, S, T)

    float* sums = (float*)d_ws;                  // B * NSEG
    float* cnts = sums + B * NSEG;               // B * NSEG
    int*   seg  = (int*)(cnts + B * NSEG);       // B * L

    seg_count_kernel<<<B, 64, 0, stream>>>(mask, sw, tw, seg, sums, cnts);
    dot_kernel<<<(B * L) / 4, 256, 0, stream>>>(tok, W, seg, sums);
    logits_kernel<<<B, 256, 0, stream>>>(sums, cnts, bias, out);
}

// Round 2
// 15.563 us; speedup vs baseline: 1.0856x; 1.0856x over previous
//
#include <hip/hip_runtime.h>
#include <hip/hip_bf16.h>

// Problem constants (fixed by the reference module)
constexpr int B    = 8;
constexpr int LS   = 256;          // L_SRC == L_TGT
constexpr int L    = 512;          // L_SRC + L_TGT
constexpr int H    = 768;
constexpr int S    = 128;          // N_SRC_WORDS
constexpr int T    = 128;          // N_TGT_WORDS
constexpr int NW   = 256;          // S + T (pooled words used)

// ---------------------------------------------------------------------------
// Kernel A: one wave per token; compute BOTH dots d_src = tok.w_src and
// d_tgt = tok.w_tgt (weights are L2-resident, so this costs no extra HBM
// traffic and removes the dependency on the segmentation map).
// Writes float2 per token into workspace. Grid: B*L/4 blocks x 256 thr.
// ---------------------------------------------------------------------------
__global__ __launch_bounds__(256) void dot2_kernel(
    const float* __restrict__ tok, const float* __restrict__ Wp,
    float2* __restrict__ dvals)
{
    const int lane  = threadIdx.x & 63;
    const int wv    = threadIdx.x >> 6;
    const int token = blockIdx.x * 4 + wv;      // 0 .. B*L-1

    const float4* t4 = reinterpret_cast<const float4*>(tok + (size_t)token * H);
    const float4* s4 = reinterpret_cast<const float4*>(Wp);
    const float4* g4 = reinterpret_cast<const float4*>(Wp + H);

    float as = 0.f, at = 0.f;
    #pragma unroll
    for (int k = 0; k < 3; ++k) {               // 3 * 64 * 4 = 768
        const float4 a = t4[lane + 64 * k];
        const float4 s = s4[lane + 64 * k];
        const float4 g = g4[lane + 64 * k];
        as += a.x * s.x + a.y * s.y + a.z * s.z + a.w * s.w;
        at += a.x * g.x + a.y * g.y + a.z * g.z + a.w * g.w;
    }
    #pragma unroll
    for (int off = 32; off; off >>= 1) {
        as += __shfl_xor(as, off);
        at += __shfl_xor(at, off);
    }
    if (lane == 0) dvals[token] = make_float2(as, at);
}

// ---------------------------------------------------------------------------
// Kernel B: one block per batch (1024 threads). Wave 0 runs the 512-token
// run-segmentation scan (8 tokens/lane + __shfl_up wave scan) into LDS,
// LDS-atomic counts; then 512 threads accumulate the selected per-token dot
// into per-segment sums; divide -> 256 pooled scalars; all 16 waves write
// the 128x128 broadcast-sum logits.
// ---------------------------------------------------------------------------
__global__ __launch_bounds__(1024) void finalize_kernel(
    const int* __restrict__ mask, const int* __restrict__ sw,
    const int* __restrict__ tw, const float2* __restrict__ dvals,
    const float* __restrict__ bias, float* __restrict__ out)
{
    const int b   = blockIdx.x;
    const int tid = threadIdx.x;

    __shared__ int   sseg[L];
    __shared__ float lsum[NW + 1];
    __shared__ float lcnt[NW + 1];
    __shared__ float pooled[NW];                // [0,S): src means, [S,NW): tgt

    if (tid < NW + 1) { lsum[tid] = 0.f; lcnt[tid] = 0.f; }
    __syncthreads();

    if (tid < 64) {                             // wave 0: segmentation scan
        const int lane = tid;
        const int base = lane * 8;

        int  wid[8]; bool val[8];
        #pragma unroll
        for (int j = 0; j < 8; ++j) {
            const int l = base + j;
            const int w = (l < LS) ? sw[b * LS + l] : tw[b * LS + (l - LS)];
            wid[j] = w;
            val[j] = (mask[b * L + l] > 0) && (w >= 0);
        }

        int pw = -2; bool pv = false;
        if (base > 0) {
            const int l = base - 1;
            pw = (l < LS) ? sw[b * LS + l] : tw[b * LS + (l - LS)];
            pv = (mask[b * L + l] > 0) && (pw >= 0);
        }

        int loc[8]; int c = 0;
        #pragma unroll
        for (int j = 0; j < 8; ++j) {
            const int nr = (val[j] && (wid[j] != pw || !pv)) ? 1 : 0;
            c += nr;
            loc[j] = c;
            pw = wid[j]; pv = val[j];
        }

        int inc = c;
        #pragma unroll
        for (int off = 1; off < 64; off <<= 1) {
            const int v = __shfl_up(inc, off);
            if (lane >= off) inc += v;
        }
        const int excl = inc - c;

        #pragma unroll
        for (int j = 0; j < 8; ++j) {
            const int rid = excl + loc[j] - 1;
            const int sg  = (val[j] && rid < NW) ? rid : NW;  // NW = dropped
            sseg[base + j] = sg;
            atomicAdd(&lcnt[sg], 1.0f);
        }
    }
    __syncthreads();

    if (tid < L) {                              // accumulate selected dots
        const int sg = sseg[tid];
        if (sg < NW) {
            const float2 d = dvals[b * L + tid];
            atomicAdd(&lsum[sg], (sg < S) ? d.x : d.y);
        }
    }
    __syncthreads();

    if (tid < NW) pooled[tid] = lsum[tid] / fmaxf(lcnt[tid], 1.f);
    __syncthreads();

    // logits[b,i,j] = pooled[i] + pooled[S+j] + b0 ; 1024 thr x 16 floats
    const float b0 = bias[0];
    const int i  = tid >> 3;                    // row 0..127
    const int jb = (tid & 7) * 16;              // 16-col slice
    const float si = pooled[i] + b0;

    float4* o = reinterpret_cast<float4*>(out + (size_t)b * S * T + i * T + jb);
    #pragma unroll
    for (int j = 0; j < 16; j += 4) {
        float4 v;
        v.x = si + pooled[S + jb + j + 0];
        v.y = si + pooled[S + jb + j + 1];
        v.z = si + pooled[S + jb + j + 2];
        v.w = si + pooled[S + jb + j + 3];
        o[j >> 2] = v;
    }
}

extern "C" void kernel_launch(void* const* d_in, const int* in_sizes, int n_in,
                              void* d_out, int out_size, void* d_ws, size_t ws_size,
                              hipStream_t stream) {
    const float* tok  = (const float*)d_in[0];   // (B, L, H) f32
    const int*   mask = (const int*)  d_in[1];   // (B, L)
    const int*   sw   = (const int*)  d_in[2];   // (B, LS)
    const int*   tw   = (const int*)  d_in[3];   // (B, LS)
    const float* W    = (const float*)d_in[4];   // (2H, 1)
    const float* bias = (const float*)d_in[5];   // (1,)
    float*       out  = (float*)d_out;           // (B, S, T)

    float2* dvals = (float2*)d_ws;               // B * L float2

    dot2_kernel<<<(B * L) / 4, 256, 0, stream>>>(tok, W, dvals);
    finalize_kernel<<<B, 1024, 0, stream>>>(mask, sw, tw, dvals, bias, out);
}